// Round 3
// baseline (535.915 us; speedup 1.0000x reference)
//
#include <hip/hip_runtime.h>

#define SLEN 200
#define NB   2048

typedef short  bf8s   __attribute__((ext_vector_type(8)));
typedef __bf16 bf16x8 __attribute__((ext_vector_type(8)));
typedef float  f4     __attribute__((ext_vector_type(4)));

__device__ __forceinline__ unsigned short f2b(float f){
  unsigned int u = __builtin_bit_cast(unsigned int, f);
  u += 0x7FFFu + ((u>>16)&1u);
  return (unsigned short)(u>>16);
}
__device__ __forceinline__ float b2f(unsigned short b){
  return __builtin_bit_cast(float, ((unsigned int)b)<<16);
}
__device__ __forceinline__ float ldf(const void* p, long i, bool bf){
  return bf ? b2f(((const unsigned short*)p)[i]) : ((const float*)p)[i];
}
__device__ __forceinline__ bf8s loadfrag(const void* p, long i, bool bf){
  bf8s r;
  if (bf) {
    r = *(const bf8s*)((const unsigned short*)p + i);
  } else {
    const float* q = (const float*)p + i;
#pragma unroll
    for (int k=0;k<8;k++) r[k] = (short)f2b(q[k]);
  }
  return r;
}
__device__ __forceinline__ bf8s fill8(unsigned short v){
  bf8s r;
#pragma unroll
  for (int k=0;k<8;k++) r[k] = (short)v;
  return r;
}
__device__ __forceinline__ float sigm(float x){ return 1.0f/(1.0f+__expf(-x)); }
__device__ __forceinline__ float tanh_(float x){
  x = fminf(fmaxf(x,-15.f),15.f);
  float e = __expf(2.f*x);
  return (e-1.f)/(e+1.f);
}
__device__ __forceinline__ f4 MF(bf8s a, bf8s b, f4 c){
  return __builtin_amdgcn_mfma_f32_16x16x32_bf16(
    __builtin_bit_cast(bf16x8,a), __builtin_bit_cast(bf16x8,b), c, 0,0,0);
}

// Runtime C/D layout probe: decodes (row,col) for each (lane, reg).
__device__ __forceinline__ void probe_cd(int lane, int* rowd, int* cold){
  f4 z = {0.f,0.f,0.f,0.f};
  const unsigned short one = 0x3F80;
  f4 p1 = MF(fill8(f2b((float)(lane&15))), fill8(one), z);
  f4 p2 = MF(fill8(one), fill8(f2b((float)(lane&15))), z);
#pragma unroll
  for (int i=0;i<4;++i){
    rowd[i] = (int)(p1[i]*(1.f/32.f)+0.5f);
    cold[i] = (int)(p2[i]*(1.f/32.f)+0.5f);
  }
}

// ---------------- K0: input dtype detector (bf16-pairs vs f32) ----------------
__global__ void k0_detect(const unsigned int* wds, int n, int* flag){
  __shared__ int cnt[256];
  int c = 0;
  for (int i = threadIdx.x; i < n; i += 256){
    unsigned e = (wds[i] >> 7) & 0xFFu;   // low-halfword bf16 exponent field
    c += (e >= 96u && e <= 160u) ? 1 : 0;
  }
  cnt[threadIdx.x] = c;
  __syncthreads();
  for (int s = 128; s > 0; s >>= 1){
    if (threadIdx.x < s) cnt[threadIdx.x] += cnt[threadIdx.x + s];
    __syncthreads();
  }
  if (threadIdx.x == 0) flag[0] = (cnt[0]*2 > n) ? 1 : 0;
}

// ---------------- K1: interest-extraction GRU scan ----------------
__global__ __launch_bounds__(256)
void k1_gru(const void* behavior, const void* Wih, const void* Whh,
            const void* bih, const void* bhh, const int* lengths,
            const int* flag, unsigned short* hidden){
  const bool bf = flag[0]!=0;
  const int tid=threadIdx.x, lane=tid&63, w=tid>>6, l15=lane&15, q=lane>>4;
  const int b0 = blockIdx.x*8;

  __shared__ alignas(16) unsigned short x_lds[16][72];
  __shared__ alignas(16) unsigned short h_bf[16][72];
  __shared__ float h_f32[8][65];

  int rowd[4], cold[4];
  probe_cd(lane, rowd, cold);

  const int jw = w*16 + l15;
  bf8s wif[3][2], whf[3][2];
#pragma unroll
  for (int G=0;G<3;++G)
#pragma unroll
    for (int kf=0;kf<2;++kf){
      long off = (long)(G*64+jw)*64 + kf*32 + q*8;
      wif[G][kf] = loadfrag(Wih, off, bf);
      whf[G][kf] = loadfrag(Whh, off, bf);
    }

  int jc[4], Ln[4]; float Br[4],Bz[4],Bin[4],Bhn[4];
#pragma unroll
  for (int i=0;i<4;++i){
    jc[i] = w*16 + cold[i];
    Br[i]  = ldf(bih,jc[i],bf)+ldf(bhh,jc[i],bf);
    Bz[i]  = ldf(bih,64+jc[i],bf)+ldf(bhh,64+jc[i],bf);
    Bin[i] = ldf(bih,128+jc[i],bf);
    Bhn[i] = ldf(bhh,128+jc[i],bf);
    Ln[i]  = (rowd[i]<8) ? lengths[b0+rowd[i]] : 0;
  }

  for (int i=tid;i<16*72;i+=256){ ((unsigned short*)x_lds)[i]=0; ((unsigned short*)h_bf)[i]=0; }
  for (int i=tid;i<8*65;i+=256) ((float*)h_f32)[i]=0.f;

  const int srow = tid>>5, kp = (tid&31)*2;
  const long xbase = ((long)(b0+srow)*SLEN)*64 + kp;
  x_lds[srow][kp]   = f2b(ldf(behavior, xbase+0, bf));
  x_lds[srow][kp+1] = f2b(ldf(behavior, xbase+1, bf));
  float xv0 = ldf(behavior, xbase+64, bf), xv1 = ldf(behavior, xbase+65, bf);
  __syncthreads();

  for (int t=0;t<SLEN;++t){
    bf8s xa0 = *(const bf8s*)&x_lds[l15][0 + q*8];
    bf8s xa1 = *(const bf8s*)&x_lds[l15][32+ q*8];
    bf8s ha0 = *(const bf8s*)&h_bf [l15][0 + q*8];
    bf8s ha1 = *(const bf8s*)&h_bf [l15][32+ q*8];
    float nv0=0.f, nv1=0.f;
    if (t+2<SLEN){
      nv0=ldf(behavior, xbase+(long)(t+2)*64,   bf);
      nv1=ldf(behavior, xbase+(long)(t+2)*64+1, bf);
    }
    f4 z4={0.f,0.f,0.f,0.f};
    f4 aIr=z4,aIz=z4,aIn=z4,aHr=z4,aHz=z4,aHn=z4;
    aIr=MF(xa0,wif[0][0],aIr); aIr=MF(xa1,wif[0][1],aIr);
    aIz=MF(xa0,wif[1][0],aIz); aIz=MF(xa1,wif[1][1],aIz);
    aIn=MF(xa0,wif[2][0],aIn); aIn=MF(xa1,wif[2][1],aIn);
    aHr=MF(ha0,whf[0][0],aHr); aHr=MF(ha1,whf[0][1],aHr);
    aHz=MF(ha0,whf[1][0],aHz); aHz=MF(ha1,whf[1][1],aHz);
    aHn=MF(ha0,whf[2][0],aHn); aHn=MF(ha1,whf[2][1],aHn);
    __syncthreads();                       // frag reads done before writes
#pragma unroll
    for (int i=0;i<4;++i){
      if (rowd[i]<8){
        float rg = sigm(aIr[i]+aHr[i]+Br[i]);
        float zg = sigm(aIz[i]+aHz[i]+Bz[i]);
        float ng = tanh_(aIn[i]+Bin[i] + rg*(aHn[i]+Bhn[i]));
        float hold = h_f32[rowd[i]][jc[i]];
        float hnew = (1.f-zg)*ng + zg*hold;
        bool valid = (t < Ln[i]);
        float hv = valid ? hnew : hold;
        h_f32[rowd[i]][jc[i]] = hv;
        h_bf [rowd[i]][jc[i]] = f2b(hv);
        hidden[((long)(b0+rowd[i])*SLEN + t)*64 + jc[i]] =
            valid ? f2b(hnew) : (unsigned short)0;
      }
    }
    if (t+1<SLEN){ x_lds[srow][kp]=f2b(xv0); x_lds[srow][kp+1]=f2b(xv1); }
    xv0=nv0; xv1=nv1;
    __syncthreads();                       // writes visible for next step
  }
}

// ---------------- K2: attention MLP + masked softmax ----------------
__global__ __launch_bounds__(256)
void k2_att(const unsigned short* hidden, const void* target, const void* A1,
            const void* b1, const void* A2, const int* lengths, const int* flag,
            float* attw){
  const bool bf = flag[0]!=0;
  const int b=blockIdx.x, tid=threadIdx.x, lane=tid&63, w=tid>>6, l15=lane&15, q=lane>>4;
  __shared__ alignas(16) unsigned short hl[208][72];
  __shared__ float tile[4][16][16];
  __shared__ float ct[64], a2s[64], tg[64], score[208], red[8];
  const int len = lengths[b];
  int rowd[4], cold[4];
  probe_cd(lane, rowd, cold);

  if (tid<64) tg[tid] = ldf(target,(long)b*64+tid,bf);
  for (int i=tid;i<208*64;i+=256){
    int row=i>>6, c=i&63;
    hl[row][c] = (row<SLEN)? hidden[((long)b*SLEN+row)*64+c] : (unsigned short)0;
  }
  bf8s a1f[4][2];
#pragma unroll
  for (int nt=0;nt<4;++nt)
#pragma unroll
    for (int kf=0;kf<2;++kf)
      a1f[nt][kf] = loadfrag(A1,(long)(nt*16+l15)*128 + kf*32 + q*8, bf);
  __syncthreads();
  if (tid<64){
    float acc = ldf(b1,tid,bf);
    for (int k=0;k<64;k++) acc += tg[k]*ldf(A1,(long)tid*128+64+k,bf);
    ct[tid]=acc; a2s[tid]=ldf(A2,tid,bf);
  }
  __syncthreads();

  for (int it=0; it<4; ++it){
    int m = it*4 + w;
    for (int i=tid;i<4*16*16;i+=256) ((float*)tile)[i]=0.f;
    __syncthreads();
    if (m<13){
      int row = m*16 + l15;
      bf8s h0 = *(const bf8s*)&hl[row][0 +q*8];
      bf8s h1 = *(const bf8s*)&hl[row][32+q*8];
      f4 z4={0.f,0.f,0.f,0.f};
      f4 acc[4];
#pragma unroll
      for (int nt=0;nt<4;++nt){
        f4 a=z4; a=MF(h0,a1f[nt][0],a); a=MF(h1,a1f[nt][1],a); acc[nt]=a;
      }
#pragma unroll
      for (int i=0;i<4;++i){
        float s=0.f;
#pragma unroll
        for (int nt=0;nt<4;++nt){
          int au = nt*16 + cold[i];
          s += fmaxf(acc[nt][i]+ct[au],0.f)*a2s[au];
        }
        tile[w][rowd[i]][cold[i]] = s;
      }
    }
    __syncthreads();
    if (tid<64){
      int tw=tid>>4, rr=tid&15, mm=it*4+tw;
      if (mm<13){
        float ssum=0.f;
#pragma unroll
        for (int c2=0;c2<16;++c2) ssum += tile[tw][rr][c2];
        score[mm*16+rr]=ssum;
      }
    }
    __syncthreads();
  }

  float sv = (tid<208)? score[tid] : -3e38f;
  bool valid = (tid<len);
  float mv = valid? sv : -3e38f;
#pragma unroll
  for (int d=32;d>0;d>>=1) mv = fmaxf(mv,__shfl_xor(mv,d));
  if (lane==0) red[w]=mv;
  __syncthreads();
  float M = fmaxf(fmaxf(red[0],red[1]),fmaxf(red[2],red[3]));
  float e = valid? __expf(sv-M):0.f;
  float sum=e;
#pragma unroll
  for (int d=32;d>0;d>>=1) sum += __shfl_xor(sum,d);
  if (lane==0) red[4+w]=sum;
  __syncthreads();
  float S = red[4]+red[5]+red[6]+red[7];
  if (tid<SLEN) attw[(long)b*SLEN+tid]=e/S;
}

// ---------------- K3: attentional GRU scan (f32 output!) ----------------
__global__ __launch_bounds__(256)
void k3_agru(const unsigned short* hidden, const float* attw,
             const void* Wr, const void* br, const void* Wz, const void* bz,
             const void* Wn, const void* bn, const int* flag,
             float* out){
  const bool bf = flag[0]!=0;
  const int tid=threadIdx.x, lane=tid&63, w=tid>>6, l15=lane&15, q=lane>>4;
  const int b0=blockIdx.x*8;
  __shared__ alignas(16) unsigned short hi_lds[16][72];
  __shared__ alignas(16) unsigned short h_bf[16][72];
  __shared__ alignas(16) unsigned short rh_bf[16][72];
  __shared__ float h_f32[8][65];
  __shared__ float att_l[8][200];

  int rowd[4], cold[4];
  probe_cd(lane, rowd, cold);
  const int jw = w*16+l15;
  bf8s wrf[2][2], wzf[2][2], wnf[2][2];
#pragma unroll
  for (int hh=0;hh<2;++hh)
#pragma unroll
    for (int kf=0;kf<2;++kf){
      long off = (long)jw*128 + hh*64 + kf*32 + q*8;
      wrf[hh][kf]=loadfrag(Wr,off,bf);
      wzf[hh][kf]=loadfrag(Wz,off,bf);
      wnf[hh][kf]=loadfrag(Wn,off,bf);
    }
  int jc[4]; float Brv[4],Bzv[4],Bnv[4];
#pragma unroll
  for (int i=0;i<4;++i){
    jc[i]=w*16+cold[i];
    Brv[i]=ldf(br,jc[i],bf); Bzv[i]=ldf(bz,jc[i],bf); Bnv[i]=ldf(bn,jc[i],bf);
  }
  for (int i=tid;i<16*72;i+=256){
    ((unsigned short*)hi_lds)[i]=0; ((unsigned short*)h_bf)[i]=0; ((unsigned short*)rh_bf)[i]=0;
  }
  for (int i=tid;i<8*65;i+=256) ((float*)h_f32)[i]=0.f;
  for (int i=tid;i<8*200;i+=256) ((float*)att_l)[i]=attw[(long)b0*SLEN+i];

  const int srow=tid>>5, kp=(tid&31)*2;
  const long hbase=((long)(b0+srow)*SLEN)*64+kp;
  hi_lds[srow][kp]  = hidden[hbase+0];
  hi_lds[srow][kp+1]= hidden[hbase+1];
  unsigned short s0=hidden[hbase+64], s1=hidden[hbase+65];
  __syncthreads();

  for (int t=0;t<SLEN;++t){
    bf8s hi0=*(const bf8s*)&hi_lds[l15][0+q*8];
    bf8s hi1=*(const bf8s*)&hi_lds[l15][32+q*8];
    bf8s hh0=*(const bf8s*)&h_bf[l15][0+q*8];
    bf8s hh1=*(const bf8s*)&h_bf[l15][32+q*8];
    unsigned short n0=0,n1=0;
    if (t+2<SLEN){ n0=hidden[hbase+(long)(t+2)*64]; n1=hidden[hbase+(long)(t+2)*64+1]; }
    f4 z4={0.f,0.f,0.f,0.f};
    f4 aR=z4,aZ=z4,aN=z4;
    aR=MF(hi0,wrf[0][0],aR); aR=MF(hi1,wrf[0][1],aR);
    aR=MF(hh0,wrf[1][0],aR); aR=MF(hh1,wrf[1][1],aR);
    aZ=MF(hi0,wzf[0][0],aZ); aZ=MF(hi1,wzf[0][1],aZ);
    aZ=MF(hh0,wzf[1][0],aZ); aZ=MF(hh1,wzf[1][1],aZ);
    aN=MF(hi0,wnf[0][0],aN); aN=MF(hi1,wnf[0][1],aN);
    __syncthreads();                      // BAR A: phase-1 LDS reads done
    float zs[4], hs[4];
#pragma unroll
    for (int i=0;i<4;++i){
      zs[i]=0.f; hs[i]=0.f;
      if (rowd[i]<8){
        float rg = sigm(aR[i]+Brv[i]);
        float zg = sigm(aZ[i]+Bzv[i]) * att_l[rowd[i]][t];
        float hold = h_f32[rowd[i]][jc[i]];
        zs[i]=zg; hs[i]=hold;
        rh_bf[rowd[i]][jc[i]] = f2b(rg*hold);
      }
    }
    if (t+1<SLEN){ hi_lds[srow][kp]=s0; hi_lds[srow][kp+1]=s1; }
    s0=n0; s1=n1;
    __syncthreads();                      // BAR B: rh ready
    bf8s ra0=*(const bf8s*)&rh_bf[l15][0+q*8];
    bf8s ra1=*(const bf8s*)&rh_bf[l15][32+q*8];
    aN=MF(ra0,wnf[1][0],aN);
    aN=MF(ra1,wnf[1][1],aN);
#pragma unroll
    for (int i=0;i<4;++i){
      if (rowd[i]<8){
        float ng = tanh_(aN[i]+Bnv[i]);
        float hnew = (1.f-zs[i])*hs[i] + zs[i]*ng;
        h_f32[rowd[i]][jc[i]]=hnew;
        h_bf [rowd[i]][jc[i]]=f2b(hnew);
      }
    }
    __syncthreads();                      // BAR C: h ready for next step
  }
#pragma unroll
  for (int i=0;i<4;++i)
    if (rowd[i]<8)
      out[(long)(b0+rowd[i])*64+jc[i]] = h_f32[rowd[i]][jc[i]];   // f32 output
}

extern "C" void kernel_launch(void* const* d_in, const int* in_sizes, int n_in,
                              void* d_out, int out_size, void* d_ws, size_t ws_size,
                              hipStream_t stream) {
  const void* behavior = d_in[0];
  const void* target   = d_in[1];
  const int*  lengths  = (const int*)d_in[2];
  const void* Wih = d_in[3];
  const void* Whh = d_in[4];
  const void* bih = d_in[5];
  const void* bhh = d_in[6];
  const void* A1  = d_in[7];
  const void* b1  = d_in[8];
  const void* A2  = d_in[9];
  const void* Wr  = d_in[10];
  const void* br  = d_in[11];
  const void* Wz  = d_in[12];
  const void* bz  = d_in[13];
  const void* Wn  = d_in[14];
  const void* bn  = d_in[15];

  int* flag = (int*)d_ws;
  unsigned short* hidden = (unsigned short*)((char*)d_ws + 256);
  float* attw = (float*)((char*)d_ws + 256 + (size_t)NB*SLEN*64*2);
  size_t needed = 256 + (size_t)NB*SLEN*64*2 + (size_t)NB*SLEN*4;
  if (ws_size < needed) return;

  k0_detect<<<1, 256, 0, stream>>>((const unsigned int*)behavior, 4096, flag);
  k1_gru  <<<NB/8, 256, 0, stream>>>(behavior, Wih, Whh, bih, bhh, lengths, flag, hidden);
  k2_att  <<<NB,   256, 0, stream>>>(hidden, target, A1, b1, A2, lengths, flag, attw);
  k3_agru <<<NB/8, 256, 0, stream>>>(hidden, attw, Wr, br, Wz, bz, Wn, bn, flag,
                                     (float*)d_out);
}

// Round 4
// 474.841 us; speedup vs baseline: 1.1286x; 1.1286x over previous
//
#include <hip/hip_runtime.h>

#define SLEN 200
#define NB   2048

typedef short  bf8s   __attribute__((ext_vector_type(8)));
typedef __bf16 bf16x8 __attribute__((ext_vector_type(8)));
typedef float  f4     __attribute__((ext_vector_type(4)));

__device__ __forceinline__ unsigned short f2b(float f){
  unsigned int u = __builtin_bit_cast(unsigned int, f);
  u += 0x7FFFu + ((u>>16)&1u);
  return (unsigned short)(u>>16);
}
__device__ __forceinline__ float b2f(unsigned short b){
  return __builtin_bit_cast(float, ((unsigned int)b)<<16);
}
__device__ __forceinline__ float ldf(const void* p, long i, bool bf){
  return bf ? b2f(((const unsigned short*)p)[i]) : ((const float*)p)[i];
}
__device__ __forceinline__ bf8s loadfrag(const void* p, long i, bool bf){
  bf8s r;
  if (bf) {
    r = *(const bf8s*)((const unsigned short*)p + i);
  } else {
    const float* q = (const float*)p + i;
#pragma unroll
    for (int k=0;k<8;k++) r[k] = (short)f2b(q[k]);
  }
  return r;
}
__device__ __forceinline__ bf8s fill8(unsigned short v){
  bf8s r;
#pragma unroll
  for (int k=0;k<8;k++) r[k] = (short)v;
  return r;
}
__device__ __forceinline__ float sigm(float x){ return 1.0f/(1.0f+__expf(-x)); }
__device__ __forceinline__ float tanh_(float x){
  x = fminf(fmaxf(x,-15.f),15.f);
  float e = __expf(2.f*x);
  return (e-1.f)/(e+1.f);
}
__device__ __forceinline__ f4 MF(bf8s a, bf8s b, f4 c){
  return __builtin_amdgcn_mfma_f32_16x16x32_bf16(
    __builtin_bit_cast(bf16x8,a), __builtin_bit_cast(bf16x8,b), c, 0,0,0);
}
// lgkm-only barrier: global prefetches (vmcnt) stay in flight across it.
__device__ __forceinline__ void sync_lds(){
  asm volatile("s_waitcnt lgkmcnt(0)" ::: "memory");
  __builtin_amdgcn_s_barrier();
  __builtin_amdgcn_sched_barrier(0);
}

// Runtime C/D layout probe: decodes (row,col) for each (lane, reg).
__device__ __forceinline__ void probe_cd(int lane, int* rowd, int* cold){
  f4 z = {0.f,0.f,0.f,0.f};
  const unsigned short one = 0x3F80;
  f4 p1 = MF(fill8(f2b((float)(lane&15))), fill8(one), z);
  f4 p2 = MF(fill8(one), fill8(f2b((float)(lane&15))), z);
#pragma unroll
  for (int i=0;i<4;++i){
    rowd[i] = (int)(p1[i]*(1.f/32.f)+0.5f);
    cold[i] = (int)(p2[i]*(1.f/32.f)+0.5f);
  }
}

// A-fragment (row=lane&15, k=(lane>>4)*8+j) loaded straight from global.
// base_el = element index of (row, k=q*8); frag1 at +32 elements.
__device__ __forceinline__ void load_afrag_pair_f32(const float* fp, bf8s& f0, bf8s& f1){
  f4 a = *(const f4*)fp, b_ = *(const f4*)(fp+4);
  f4 c = *(const f4*)(fp+32), d = *(const f4*)(fp+36);
#pragma unroll
  for (int j=0;j<4;++j){
    f0[j]=(short)f2b(a[j]); f0[4+j]=(short)f2b(b_[j]);
    f1[j]=(short)f2b(c[j]); f1[4+j]=(short)f2b(d[j]);
  }
}

// ---------------- K0: input dtype detector (bf16-pairs vs f32) ----------------
__global__ void k0_detect(const unsigned int* wds, int n, int* flag){
  __shared__ int cnt[256];
  int c = 0;
  for (int i = threadIdx.x; i < n; i += 256){
    unsigned e = (wds[i] >> 7) & 0xFFu;
    c += (e >= 96u && e <= 160u) ? 1 : 0;
  }
  cnt[threadIdx.x] = c;
  __syncthreads();
  for (int s = 128; s > 0; s >>= 1){
    if (threadIdx.x < s) cnt[threadIdx.x] += cnt[threadIdx.x + s];
    __syncthreads();
  }
  if (threadIdx.x == 0) flag[0] = (cnt[0]*2 > n) ? 1 : 0;
}

// ---------------- K1: interest-extraction GRU scan ----------------
// 8 rows/block, 4 waves; wave w owns h-cols [16w,16w+16). x loads direct
// to A-frags (no LDS); h double-buffered in LDS; 1 raw barrier/step.
__global__ __launch_bounds__(256)
void k1_gru(const void* behavior, const void* Wih, const void* Whh,
            const void* bih, const void* bhh, const int* lengths,
            const int* flag, unsigned short* hidden){
  const bool bf = flag[0]!=0;
  const int tid=threadIdx.x, lane=tid&63, w=tid>>6, l15=lane&15, q=lane>>4;
  const int b0 = blockIdx.x*8;

  __shared__ alignas(16) unsigned short h_lds[2][16][72];

  int rowd[4], cold[4];
  probe_cd(lane, rowd, cold);

  const int jw = w*16 + l15;
  bf8s wif[3][2], whf[3][2];
#pragma unroll
  for (int G=0;G<3;++G)
#pragma unroll
    for (int kf=0;kf<2;++kf){
      long off = (long)(G*64+jw)*64 + kf*32 + q*8;
      wif[G][kf] = loadfrag(Wih, off, bf);
      whf[G][kf] = loadfrag(Whh, off, bf);
    }

  int jc[4], Ln[4]; float Br[4],Bz[4],Bin[4],Bhn[4];
#pragma unroll
  for (int i=0;i<4;++i){
    jc[i] = w*16 + cold[i];
    Br[i]  = ldf(bih,jc[i],bf)+ldf(bhh,jc[i],bf);
    Bz[i]  = ldf(bih,64+jc[i],bf)+ldf(bhh,64+jc[i],bf);
    Bin[i] = ldf(bih,128+jc[i],bf);
    Bhn[i] = ldf(bhh,128+jc[i],bf);
    Ln[i]  = (rowd[i]<8) ? lengths[b0+rowd[i]] : 0;
  }

  for (int i=tid;i<2*16*72;i+=256) ((unsigned short*)h_lds)[i]=0;

  float hreg[4] = {0.f,0.f,0.f,0.f};

  // x pipeline, 2-deep register prefetch, direct A-layout.
  const long xrow = b0 + (l15&7);
  const long xstep = 64;                      // elements per t
  const long xorig = ((long)xrow*SLEN)*64 + q*8;
  const unsigned short* bp = (const unsigned short*)behavior;
  const float*          fp = (const float*)behavior;

  bf8s xb00,xb01, xb10,xb11;                  // bf16 pipeline
  f4   r00,r01,r02,r03, r10,r11,r12,r13;     // f32 raw pipeline
  if (bf){
    xb00 = *(const bf8s*)(bp + xorig);        xb01 = *(const bf8s*)(bp + xorig + 32);
    xb10 = *(const bf8s*)(bp + xorig + 64);   xb11 = *(const bf8s*)(bp + xorig + 96);
  } else {
    r00=*(const f4*)(fp+xorig);    r01=*(const f4*)(fp+xorig+4);
    r02=*(const f4*)(fp+xorig+32); r03=*(const f4*)(fp+xorig+36);
    r10=*(const f4*)(fp+xorig+64); r11=*(const f4*)(fp+xorig+68);
    r12=*(const f4*)(fp+xorig+96); r13=*(const f4*)(fp+xorig+100);
  }
  sync_lds();                                  // h_lds zero visible

  for (int t=0;t<SLEN;++t){
    // prefetch t+2
    long pofs = xorig + (long)((t+2<SLEN)?t+2:SLEN-1)*xstep;
    bf8s nb0,nb1; f4 n0,n1,n2,n3;
    if (bf){ nb0=*(const bf8s*)(bp+pofs); nb1=*(const bf8s*)(bp+pofs+32); }
    else   { n0=*(const f4*)(fp+pofs);    n1=*(const f4*)(fp+pofs+4);
             n2=*(const f4*)(fp+pofs+32); n3=*(const f4*)(fp+pofs+36); }

    // h fragments (LDS, written last step by all waves)
    bf8s ha0 = *(const bf8s*)&h_lds[t&1][l15][q*8];
    bf8s ha1 = *(const bf8s*)&h_lds[t&1][l15][32+q*8];

    // x fragments for step t
    bf8s xa0, xa1;
    if (bf){ xa0 = xb00; xa1 = xb01; }
    else {
#pragma unroll
      for (int j=0;j<4;++j){
        xa0[j]=(short)f2b(r00[j]); xa0[4+j]=(short)f2b(r01[j]);
        xa1[j]=(short)f2b(r02[j]); xa1[4+j]=(short)f2b(r03[j]);
      }
    }

    f4 Tr  = {Br[0],Br[1],Br[2],Br[3]};
    f4 Tz  = {Bz[0],Bz[1],Bz[2],Bz[3]};
    f4 Txn = {Bin[0],Bin[1],Bin[2],Bin[3]};
    f4 Thn = {Bhn[0],Bhn[1],Bhn[2],Bhn[3]};
    Tr =MF(xa0,wif[0][0],Tr );  Tr =MF(xa1,wif[0][1],Tr );
    Tz =MF(xa0,wif[1][0],Tz );  Tz =MF(xa1,wif[1][1],Tz );
    Txn=MF(xa0,wif[2][0],Txn);  Txn=MF(xa1,wif[2][1],Txn);
    Tr =MF(ha0,whf[0][0],Tr );  Tr =MF(ha1,whf[0][1],Tr );
    Tz =MF(ha0,whf[1][0],Tz );  Tz =MF(ha1,whf[1][1],Tz );
    Thn=MF(ha0,whf[2][0],Thn);  Thn=MF(ha1,whf[2][1],Thn);

    const int nbuf = (t+1)&1;
#pragma unroll
    for (int i=0;i<4;++i){
      if (rowd[i]<8){
        float rg = sigm(Tr[i]);
        float zg = sigm(Tz[i]);
        float ng = tanh_(Txn[i] + rg*Thn[i]);
        float hold = hreg[i];
        float hnew = (1.f-zg)*ng + zg*hold;
        bool valid = (t < Ln[i]);
        float hv = valid ? hnew : hold;
        hreg[i] = hv;
        h_lds[nbuf][rowd[i]][jc[i]] = f2b(hv);
        hidden[((long)(b0+rowd[i])*SLEN + t)*64 + jc[i]] =
            valid ? f2b(hnew) : (unsigned short)0;
      }
    }
    // rotate pipeline
    if (bf){ xb00=xb10; xb01=xb11; xb10=nb0; xb11=nb1; }
    else   { r00=r10; r01=r11; r02=r12; r03=r13; r10=n0; r11=n1; r12=n2; r13=n3; }
    sync_lds();                               // h_lds[nbuf] visible
  }
}

// ---------------- K2: attention MLP + masked softmax ----------------
__global__ __launch_bounds__(256)
void k2_att(const unsigned short* hidden, const void* target, const void* A1,
            const void* b1, const void* A2, const int* lengths, const int* flag,
            float* attw){
  const bool bf = flag[0]!=0;
  const int b=blockIdx.x, tid=threadIdx.x, lane=tid&63, w=tid>>6, l15=lane&15, q=lane>>4;
  __shared__ alignas(16) unsigned short hl[208][72];
  __shared__ float ctp[4][64];
  __shared__ float ct[64], a2s[64], tg[64], score[208], red[8];
  const int len = lengths[b];
  int rowd[4], cold[4];
  probe_cd(lane, rowd, cold);

  if (tid<64){ tg[tid] = ldf(target,(long)b*64+tid,bf); a2s[tid]=ldf(A2,tid,bf); }
  for (int i=tid;i<208*8;i+=256){
    int row=i>>3, c8=(i&7)*8;
    uint4 v = {0u,0u,0u,0u};
    if (row<SLEN) v = *(const uint4*)&hidden[((long)b*SLEN+row)*64 + c8];
    *(uint4*)&hl[row][c8] = v;
  }
  bf8s a1f[4][2];
#pragma unroll
  for (int nt=0;nt<4;++nt)
#pragma unroll
    for (int kf=0;kf<2;++kf)
      a1f[nt][kf] = loadfrag(A1,(long)(nt*16+l15)*128 + kf*32 + q*8, bf);
  __syncthreads();

  { // ct[a] = b1[a] + sum_k tg[k]*A1[a][64+k], parallel over (a, kgroup)
    int a = tid&63, g = tid>>6;
    float part = 0.f;
#pragma unroll
    for (int k=0;k<16;++k) part += tg[g*16+k]*ldf(A1,(long)a*128+64+g*16+k,bf);
    ctp[g][a] = part;
  }
  __syncthreads();
  if (tid<64) ct[tid] = ldf(b1,tid,bf) + ctp[0][tid]+ctp[1][tid]+ctp[2][tid]+ctp[3][tid];
  __syncthreads();

#pragma unroll
  for (int it=0; it<4; ++it){
    int m = it*4 + w;
    if (m<13){
      int row = m*16 + l15;
      bf8s h0 = *(const bf8s*)&hl[row][q*8];
      bf8s h1 = *(const bf8s*)&hl[row][32+q*8];
      f4 z4={0.f,0.f,0.f,0.f};
      f4 acc[4];
#pragma unroll
      for (int nt=0;nt<4;++nt){
        f4 a=z4; a=MF(h0,a1f[nt][0],a); a=MF(h1,a1f[nt][1],a); acc[nt]=a;
      }
#pragma unroll
      for (int i=0;i<4;++i){
        float s=0.f;
#pragma unroll
        for (int nt=0;nt<4;++nt){
          int au = nt*16 + cold[i];
          s += fmaxf(acc[nt][i]+ct[au],0.f)*a2s[au];
        }
#pragma unroll
        for (int d=1; d<16; d<<=1) s += __shfl_xor(s,d);
        if (l15==0) score[m*16+rowd[i]] = s;
      }
    }
  }
  __syncthreads();

  float sv = (tid<208)? score[tid] : -3e38f;
  bool valid = (tid<len);
  float mv = valid? sv : -3e38f;
#pragma unroll
  for (int d=32;d>0;d>>=1) mv = fmaxf(mv,__shfl_xor(mv,d));
  if (lane==0) red[w]=mv;
  __syncthreads();
  float M = fmaxf(fmaxf(red[0],red[1]),fmaxf(red[2],red[3]));
  float e = valid? __expf(sv-M):0.f;
  float sum=e;
#pragma unroll
  for (int d=32;d>0;d>>=1) sum += __shfl_xor(sum,d);
  if (lane==0) red[4+w]=sum;
  __syncthreads();
  float S = red[4]+red[5]+red[6]+red[7];
  if (tid<SLEN) attw[(long)b*SLEN+tid]=e/S;
}

// ---------------- K3: attentional GRU scan ----------------
// hi direct-loaded to A-frags from bf16 hidden; h + r*h via LDS; 2 raw barriers.
__global__ __launch_bounds__(256)
void k3_agru(const unsigned short* hidden, const float* attw,
             const void* Wr, const void* br, const void* Wz, const void* bz,
             const void* Wn, const void* bn, const int* flag,
             float* out){
  const bool bf = flag[0]!=0;
  const int tid=threadIdx.x, lane=tid&63, w=tid>>6, l15=lane&15, q=lane>>4;
  const int b0=blockIdx.x*8;
  __shared__ alignas(16) unsigned short h_lds[2][16][72];
  __shared__ alignas(16) unsigned short rh_lds[16][72];
  __shared__ float att_l[8*SLEN];

  int rowd[4], cold[4];
  probe_cd(lane, rowd, cold);
  const int jw = w*16+l15;
  bf8s wrf[2][2], wzf[2][2], wnf[2][2];   // [half: 0=hi,1=h][kf]
#pragma unroll
  for (int hh=0;hh<2;++hh)
#pragma unroll
    for (int kf=0;kf<2;++kf){
      long off = (long)jw*128 + hh*64 + kf*32 + q*8;
      wrf[hh][kf]=loadfrag(Wr,off,bf);
      wzf[hh][kf]=loadfrag(Wz,off,bf);
      wnf[hh][kf]=loadfrag(Wn,off,bf);
    }
  int jc[4]; float Brv[4],Bzv[4],Bnv[4];
#pragma unroll
  for (int i=0;i<4;++i){
    jc[i]=w*16+cold[i];
    Brv[i]=ldf(br,jc[i],bf); Bzv[i]=ldf(bz,jc[i],bf); Bnv[i]=ldf(bn,jc[i],bf);
  }
  for (int i=tid;i<2*16*72;i+=256) ((unsigned short*)h_lds)[i]=0;
  for (int i=tid;i<16*72;i+=256)   ((unsigned short*)rh_lds)[i]=0;
  for (int i=tid;i<8*SLEN;i+=256)  att_l[i]=attw[(long)b0*SLEN+i];

  float hreg[4] = {0.f,0.f,0.f,0.f};

  // hi pipeline (always bf16, from ws hidden)
  const long hrow = b0 + (l15&15 & 7);
  const long horig = ((long)hrow*SLEN)*64 + q*8;
  bf8s hb00,hb01, hb10,hb11;
  hb00 = *(const bf8s*)(hidden + horig);      hb01 = *(const bf8s*)(hidden + horig + 32);
  hb10 = *(const bf8s*)(hidden + horig + 64); hb11 = *(const bf8s*)(hidden + horig + 96);
  sync_lds();

  for (int t=0;t<SLEN;++t){
    long pofs = horig + (long)((t+2<SLEN)?t+2:SLEN-1)*64;
    bf8s nb0 = *(const bf8s*)(hidden + pofs);
    bf8s nb1 = *(const bf8s*)(hidden + pofs + 32);

    bf8s ha0 = *(const bf8s*)&h_lds[t&1][l15][q*8];
    bf8s ha1 = *(const bf8s*)&h_lds[t&1][l15][32+q*8];

    f4 Tr = {Brv[0],Brv[1],Brv[2],Brv[3]};
    f4 Tz = {Bzv[0],Bzv[1],Bzv[2],Bzv[3]};
    f4 Tn = {Bnv[0],Bnv[1],Bnv[2],Bnv[3]};
    Tr=MF(hb00,wrf[0][0],Tr); Tr=MF(hb01,wrf[0][1],Tr);
    Tz=MF(hb00,wzf[0][0],Tz); Tz=MF(hb01,wzf[0][1],Tz);
    Tn=MF(hb00,wnf[0][0],Tn); Tn=MF(hb01,wnf[0][1],Tn);
    Tr=MF(ha0, wrf[1][0],Tr); Tr=MF(ha1, wrf[1][1],Tr);
    Tz=MF(ha0, wzf[1][0],Tz); Tz=MF(ha1, wzf[1][1],Tz);

    float zs[4], hs[4];
#pragma unroll
    for (int i=0;i<4;++i){
      zs[i]=0.f; hs[i]=0.f;
      if (rowd[i]<8){
        float rg = sigm(Tr[i]);
        float zg = sigm(Tz[i]) * att_l[rowd[i]*SLEN + t];
        float hold = hreg[i];
        zs[i]=zg; hs[i]=hold;
        rh_lds[rowd[i]][jc[i]] = f2b(rg*hold);
      }
    }
    sync_lds();                               // rh visible

    bf8s ra0 = *(const bf8s*)&rh_lds[l15][q*8];
    bf8s ra1 = *(const bf8s*)&rh_lds[l15][32+q*8];
    Tn=MF(ra0,wnf[1][0],Tn); Tn=MF(ra1,wnf[1][1],Tn);

    const int nbuf = (t+1)&1;
#pragma unroll
    for (int i=0;i<4;++i){
      if (rowd[i]<8){
        float ng = tanh_(Tn[i]);
        float hnew = (1.f-zs[i])*hs[i] + zs[i]*ng;
        hreg[i] = hnew;
        h_lds[nbuf][rowd[i]][jc[i]] = f2b(hnew);
      }
    }
    hb00=hb10; hb01=hb11; hb10=nb0; hb11=nb1;
    sync_lds();                               // h visible; rh reads drained
  }
#pragma unroll
  for (int i=0;i<4;++i)
    if (rowd[i]<8)
      out[(long)(b0+rowd[i])*64+jc[i]] = hreg[i];
}

extern "C" void kernel_launch(void* const* d_in, const int* in_sizes, int n_in,
                              void* d_out, int out_size, void* d_ws, size_t ws_size,
                              hipStream_t stream) {
  const void* behavior = d_in[0];
  const void* target   = d_in[1];
  const int*  lengths  = (const int*)d_in[2];
  const void* Wih = d_in[3];
  const void* Whh = d_in[4];
  const void* bih = d_in[5];
  const void* bhh = d_in[6];
  const void* A1  = d_in[7];
  const void* b1  = d_in[8];
  const void* A2  = d_in[9];
  const void* Wr  = d_in[10];
  const void* br  = d_in[11];
  const void* Wz  = d_in[12];
  const void* bz  = d_in[13];
  const void* Wn  = d_in[14];
  const void* bn  = d_in[15];

  int* flag = (int*)d_ws;
  unsigned short* hidden = (unsigned short*)((char*)d_ws + 256);
  float* attw = (float*)((char*)d_ws + 256 + (size_t)NB*SLEN*64*2);
  size_t needed = 256 + (size_t)NB*SLEN*64*2 + (size_t)NB*SLEN*4;
  if (ws_size < needed) return;

  k0_detect<<<1, 256, 0, stream>>>((const unsigned int*)behavior, 4096, flag);
  k1_gru  <<<NB/8, 256, 0, stream>>>(behavior, Wih, Whh, bih, bhh, lengths, flag, hidden);
  k2_att  <<<NB,   256, 0, stream>>>(hidden, target, A1, b1, A2, lengths, flag, attw);
  k3_agru <<<NB/8, 256, 0, stream>>>(hidden, attw, Wr, br, Wz, bz, Wn, bn, flag,
                                     (float*)d_out);
}

// Round 5
// 380.737 us; speedup vs baseline: 1.4076x; 1.2472x over previous
//
#include <hip/hip_runtime.h>

#define SLEN 200
#define NB   2048

typedef short  bf8s   __attribute__((ext_vector_type(8)));
typedef __bf16 bf16x8 __attribute__((ext_vector_type(8)));
typedef float  f4     __attribute__((ext_vector_type(4)));

__device__ __forceinline__ short fb1(float x){ __bf16 b=(__bf16)x; return __builtin_bit_cast(short,b); }
__device__ __forceinline__ float b2f(unsigned short b){
  return __builtin_bit_cast(float, ((unsigned int)b)<<16);
}
__device__ __forceinline__ float ldf(const void* p, long i, bool bf){
  return bf ? b2f(((const unsigned short*)p)[i]) : ((const float*)p)[i];
}
__device__ __forceinline__ bf8s loadfrag(const void* p, long i, bool bf){
  bf8s r;
  if (bf) {
    r = *(const bf8s*)((const unsigned short*)p + i);
  } else {
    const float* q = (const float*)p + i;
#pragma unroll
    for (int k=0;k<8;k++) r[k] = fb1(q[k]);
  }
  return r;
}
__device__ __forceinline__ float rcp_(float x){ return __builtin_amdgcn_rcpf(x); }
__device__ __forceinline__ float sigm(float x){ return rcp_(1.f + __expf(-x)); }   // inf-safe
__device__ __forceinline__ float tanh_(float x){ return 1.f - 2.f*rcp_(1.f + __expf(2.f*x)); } // inf-safe
__device__ __forceinline__ f4 MF(bf8s a, bf8s b, f4 c){
  return __builtin_amdgcn_mfma_f32_16x16x32_bf16(
    __builtin_bit_cast(bf16x8,a), __builtin_bit_cast(bf16x8,b), c, 0,0,0);
}
// lgkm-only barrier: global prefetches (vmcnt) stay in flight across it.
__device__ __forceinline__ void sync_lds(){
  asm volatile("s_waitcnt lgkmcnt(0)" ::: "memory");
  __builtin_amdgcn_s_barrier();
  __builtin_amdgcn_sched_barrier(0);
}
// Hard-coded MFMA 16x16x32 layouts (validated by round-3/4 pass):
//   A: row=lane&15, k=8*(lane>>4)+j ; C/D: col=lane&15, row=4*(lane>>4)+reg.

// ---------------- K0: input dtype detector ----------------
__global__ void k0_detect(const unsigned int* wds, int n, int* flag){
  __shared__ int cnt[256];
  int c = 0;
  for (int i = threadIdx.x; i < n; i += 256){
    unsigned e = (wds[i] >> 7) & 0xFFu;
    c += (e >= 96u && e <= 160u) ? 1 : 0;
  }
  cnt[threadIdx.x] = c;
  __syncthreads();
  for (int s = 128; s > 0; s >>= 1){
    if (threadIdx.x < s) cnt[threadIdx.x] += cnt[threadIdx.x + s];
    __syncthreads();
  }
  if (threadIdx.x == 0) flag[0] = (cnt[0]*2 > n) ? 1 : 0;
}

// ---------------- K0b: counting sort of rows by length ----------------
__global__ __launch_bounds__(256)
void k0_sort(const int* lengths, int* perm){
  __shared__ int hist[256];
  __shared__ int base[256];
  hist[threadIdx.x]=0;
  __syncthreads();
  for (int i=threadIdx.x;i<NB;i+=256) atomicAdd(&hist[lengths[i]&255],1);
  __syncthreads();
  if (threadIdx.x==0){ int acc=0; for (int j=0;j<256;++j){ base[j]=acc; acc+=hist[j]; } }
  __syncthreads();
  for (int i=threadIdx.x;i<NB;i+=256){
    int l=lengths[i]&255;
    int p=atomicAdd(&base[l],1);
    perm[p]=i;
  }
}

// ---------------- K1: interest-extraction GRU scan ----------------
// 8 sorted rows/block; 4 waves; wave w owns gate-cols [16w,16w+16).
__global__ __launch_bounds__(256)
void k1_gru(const void* behavior, const void* Wih, const void* Whh,
            const void* bih, const void* bhh, const int* lengths,
            const int* perm, const int* flag, unsigned short* hidden){
  const bool bf = flag[0]!=0;
  const int tid=threadIdx.x, lane=tid&63, w=tid>>6, l15=lane&15, q=lane>>4;
  const int g0 = blockIdx.x*8;

  __shared__ alignas(16) unsigned short h_lds[2][16][72];
  __shared__ int rows_s[8], len_s[8];

  if (tid<8){ int r=perm[g0+tid]; rows_s[tid]=r; len_s[tid]=lengths[r]; }
  for (int i=tid;i<2*16*72;i+=256) ((unsigned short*)h_lds)[i]=0;

  const int jc = w*16 + l15;
  bf8s wif[3][2], whf[3][2];
#pragma unroll
  for (int G=0;G<3;++G)
#pragma unroll
    for (int kf=0;kf<2;++kf){
      long off = (long)(G*64+jc)*64 + kf*32 + q*8;
      wif[G][kf] = loadfrag(Wih, off, bf);
      whf[G][kf] = loadfrag(Whh, off, bf);
    }
  const float Br  = ldf(bih,jc,bf)+ldf(bhh,jc,bf);
  const float Bz  = ldf(bih,64+jc,bf)+ldf(bhh,64+jc,bf);
  const float Bin = ldf(bih,128+jc,bf);
  const float Bhn = ldf(bhh,128+jc,bf);
  __syncthreads();                         // rows_s/len_s + h_lds zero visible

  int maxlen = 0;
#pragma unroll
  for (int i=0;i<8;++i) maxlen = max(maxlen, len_s[i]);

  int Ln[4]={0,0,0,0}; unsigned off_[4]={0,0,0,0};
  if (q<2){
#pragma unroll
    for (int i=0;i<4;++i){
      int s = 4*q+i;
      Ln[i]   = len_s[s];
      off_[i] = (unsigned)rows_s[s]*(SLEN*64) + jc;
    }
  }
  float hreg[4] = {0.f,0.f,0.f,0.f};

  const long xorig = ((long)rows_s[l15&7]*SLEN)*64 + q*8;
  const unsigned short* bp = (const unsigned short*)behavior;
  const float*          fp = (const float*)behavior;
  const int ml1 = maxlen-1;

  bf8s xb00,xb01, xb10,xb11;
  f4   r00,r01,r02,r03, r10,r11,r12,r13;
  {
    long o0 = xorig, o1 = xorig + (long)min(1,ml1)*64;
    if (bf){
      xb00=*(const bf8s*)(bp+o0); xb01=*(const bf8s*)(bp+o0+32);
      xb10=*(const bf8s*)(bp+o1); xb11=*(const bf8s*)(bp+o1+32);
    } else {
      r00=*(const f4*)(fp+o0);    r01=*(const f4*)(fp+o0+4);
      r02=*(const f4*)(fp+o0+32); r03=*(const f4*)(fp+o0+36);
      r10=*(const f4*)(fp+o1);    r11=*(const f4*)(fp+o1+4);
      r12=*(const f4*)(fp+o1+32); r13=*(const f4*)(fp+o1+36);
    }
  }

  for (int t=0;t<maxlen;++t){
    long pofs = xorig + (long)min(t+2,ml1)*64;
    bf8s nb0,nb1; f4 n0,n1,n2,n3;
    if (bf){ nb0=*(const bf8s*)(bp+pofs); nb1=*(const bf8s*)(bp+pofs+32); }
    else   { n0=*(const f4*)(fp+pofs);    n1=*(const f4*)(fp+pofs+4);
             n2=*(const f4*)(fp+pofs+32); n3=*(const f4*)(fp+pofs+36); }

    bf8s ha0 = *(const bf8s*)&h_lds[t&1][l15][q*8];
    bf8s ha1 = *(const bf8s*)&h_lds[t&1][l15][32+q*8];

    bf8s xa0, xa1;
    if (bf){ xa0 = xb00; xa1 = xb01; }
    else {
#pragma unroll
      for (int j=0;j<4;++j){
        xa0[j]=fb1(r00[j]); xa0[4+j]=fb1(r01[j]);
        xa1[j]=fb1(r02[j]); xa1[4+j]=fb1(r03[j]);
      }
    }

    f4 Tr  = {Br,Br,Br,Br};
    f4 Tz  = {Bz,Bz,Bz,Bz};
    f4 Txn = {Bin,Bin,Bin,Bin};
    f4 Thn = {Bhn,Bhn,Bhn,Bhn};
    Tr =MF(xa0,wif[0][0],Tr );  Tr =MF(xa1,wif[0][1],Tr );
    Tz =MF(xa0,wif[1][0],Tz );  Tz =MF(xa1,wif[1][1],Tz );
    Txn=MF(xa0,wif[2][0],Txn);  Txn=MF(xa1,wif[2][1],Txn);
    Tr =MF(ha0,whf[0][0],Tr );  Tr =MF(ha1,whf[0][1],Tr );
    Tz =MF(ha0,whf[1][0],Tz );  Tz =MF(ha1,whf[1][1],Tz );
    Thn=MF(ha0,whf[2][0],Thn);  Thn=MF(ha1,whf[2][1],Thn);

    const int nb_=(t+1)&1;
    if (q<2){
#pragma unroll
      for (int i=0;i<4;++i){
        float rg = sigm(Tr[i]);
        float zg = sigm(Tz[i]);
        float ng = tanh_(Txn[i] + rg*Thn[i]);
        float hold = hreg[i];
        float hnew = (1.f-zg)*ng + zg*hold;
        bool valid = (t < Ln[i]);
        float hv = valid ? hnew : hold;
        hreg[i] = hv;
        h_lds[nb_][4*q+i][jc] = (unsigned short)fb1(hv);
        if (valid) hidden[off_[i]] = (unsigned short)fb1(hnew);
        off_[i] += 64;
      }
    }
    if (bf){ xb00=xb10; xb01=xb11; xb10=nb0; xb11=nb1; }
    else   { r00=r10; r01=r11; r02=r12; r03=r13; r10=n0; r11=n1; r12=n2; r13=n3; }
    sync_lds();
  }
}

// ---------------- K2: attention MLP + masked softmax ----------------
__global__ __launch_bounds__(256)
void k2_att(const unsigned short* hidden, const void* target, const void* A1,
            const void* b1, const void* A2, const int* lengths, const int* flag,
            float* attw){
  const bool bf = flag[0]!=0;
  const int b=blockIdx.x, tid=threadIdx.x, lane=tid&63, w=tid>>6, l15=lane&15, q=lane>>4;
  __shared__ alignas(16) unsigned short hl[208][72];
  __shared__ float ctp[4][64];
  __shared__ float ct[64], a2s[64], tg[64], score[208], red[8];
  const int len = lengths[b];
  int mtiles = (len+15)>>4; if (mtiles>13) mtiles=13;

  if (tid<64){ tg[tid] = ldf(target,(long)b*64+tid,bf); a2s[tid]=ldf(A2,tid,bf); }
  for (int i=tid;i<mtiles*16*8;i+=256){
    int row=i>>3, c8=(i&7)*8;
    uint4 v = {0u,0u,0u,0u};
    if (row<SLEN) v = *(const uint4*)&hidden[((long)b*SLEN+row)*64 + c8];
    *(uint4*)&hl[row][c8] = v;
  }
  bf8s a1f[4][2];
#pragma unroll
  for (int nt=0;nt<4;++nt)
#pragma unroll
    for (int kf=0;kf<2;++kf)
      a1f[nt][kf] = loadfrag(A1,(long)(nt*16+l15)*128 + kf*32 + q*8, bf);
  __syncthreads();

  {
    int a = tid&63, g = tid>>6;
    float part = 0.f;
#pragma unroll
    for (int k=0;k<16;++k) part += tg[g*16+k]*ldf(A1,(long)a*128+64+g*16+k,bf);
    ctp[g][a] = part;
  }
  __syncthreads();
  if (tid<64) ct[tid] = ldf(b1,tid,bf) + ctp[0][tid]+ctp[1][tid]+ctp[2][tid]+ctp[3][tid];
  __syncthreads();

  for (int m=w; m<mtiles; m+=4){
    int row = m*16 + l15;
    bf8s h0 = *(const bf8s*)&hl[row][q*8];
    bf8s h1 = *(const bf8s*)&hl[row][32+q*8];
    f4 z4={0.f,0.f,0.f,0.f};
    f4 acc[4];
#pragma unroll
    for (int nt=0;nt<4;++nt){
      f4 a=z4; a=MF(h0,a1f[nt][0],a); a=MF(h1,a1f[nt][1],a); acc[nt]=a;
    }
#pragma unroll
    for (int i=0;i<4;++i){
      float s=0.f;
#pragma unroll
      for (int nt=0;nt<4;++nt){
        int au = nt*16 + l15;
        s += fmaxf(acc[nt][i]+ct[au],0.f)*a2s[au];
      }
#pragma unroll
      for (int d=1; d<16; d<<=1) s += __shfl_xor(s,d);
      if (l15==0) score[m*16+4*q+i] = s;
    }
  }
  __syncthreads();

  bool valid = (tid<len);
  float sv = (tid<208 && valid)? score[tid] : -3e38f;
  float mv = sv;
#pragma unroll
  for (int d=32;d>0;d>>=1) mv = fmaxf(mv,__shfl_xor(mv,d));
  if (lane==0) red[w]=mv;
  __syncthreads();
  float M = fmaxf(fmaxf(red[0],red[1]),fmaxf(red[2],red[3]));
  float e = valid? __expf(sv-M):0.f;
  float sum=e;
#pragma unroll
  for (int d=32;d>0;d>>=1) sum += __shfl_xor(sum,d);
  if (lane==0) red[4+w]=sum;
  __syncthreads();
  float S = red[4]+red[5]+red[6]+red[7];
  float Si = rcp_(S);
  if (tid<SLEN) attw[(long)b*SLEN+tid]=e*Si;
}

// ---------------- K3: attentional GRU scan ----------------
__global__ __launch_bounds__(256)
void k3_agru(const unsigned short* hidden, const float* attw,
             const void* Wr, const void* br, const void* Wz, const void* bz,
             const void* Wn, const void* bn, const int* lengths,
             const int* perm, const int* flag, float* out){
  const bool bf = flag[0]!=0;
  const int tid=threadIdx.x, lane=tid&63, w=tid>>6, l15=lane&15, q=lane>>4;
  const int g0=blockIdx.x*8;
  __shared__ alignas(16) unsigned short h_lds[2][16][72];
  __shared__ alignas(16) unsigned short rh_lds[16][72];
  __shared__ float att_l[8*SLEN];
  __shared__ int rows_s[8], len_s[8];

  if (tid<8){ int r=perm[g0+tid]; rows_s[tid]=r; len_s[tid]=lengths[r]; }
  for (int i=tid;i<2*16*72;i+=256) ((unsigned short*)h_lds)[i]=0;
  for (int i=tid;i<16*72;i+=256)   ((unsigned short*)rh_lds)[i]=0;

  const int jc = w*16+l15;
  bf8s wrf[2][2], wzf[2][2], wnf[2][2];
#pragma unroll
  for (int hh=0;hh<2;++hh)
#pragma unroll
    for (int kf=0;kf<2;++kf){
      long off = (long)jc*128 + hh*64 + kf*32 + q*8;
      wrf[hh][kf]=loadfrag(Wr,off,bf);
      wzf[hh][kf]=loadfrag(Wz,off,bf);
      wnf[hh][kf]=loadfrag(Wn,off,bf);
    }
  const float Brv=ldf(br,jc,bf), Bzv=ldf(bz,jc,bf), Bnv=ldf(bn,jc,bf);
  __syncthreads();                         // rows_s ready

  for (int i=tid;i<8*SLEN;i+=256){
    int s=i/SLEN, t=i-s*SLEN;
    att_l[i]=attw[(long)rows_s[s]*SLEN+t];
  }

  int maxlen=0;
#pragma unroll
  for (int i=0;i<8;++i) maxlen = max(maxlen, len_s[i]);
  const int ml1 = maxlen-1;

  float hreg[4] = {0.f,0.f,0.f,0.f};
  const long horig = ((long)rows_s[l15&7]*SLEN)*64 + q*8;

  bf8s hb00,hb01, hb10,hb11;
  {
    long o0=horig, o1=horig+(long)min(1,ml1)*64;
    hb00=*(const bf8s*)(hidden+o0); hb01=*(const bf8s*)(hidden+o0+32);
    hb10=*(const bf8s*)(hidden+o1); hb11=*(const bf8s*)(hidden+o1+32);
  }
  __syncthreads();                         // att_l + h_lds zero visible

  for (int t=0;t<maxlen;++t){
    long pofs = horig + (long)min(t+2,ml1)*64;
    bf8s nb0 = *(const bf8s*)(hidden + pofs);
    bf8s nb1 = *(const bf8s*)(hidden + pofs + 32);

    bf8s ha0 = *(const bf8s*)&h_lds[t&1][l15][q*8];
    bf8s ha1 = *(const bf8s*)&h_lds[t&1][l15][32+q*8];

    f4 Tr = {Brv,Brv,Brv,Brv};
    f4 Tz = {Bzv,Bzv,Bzv,Bzv};
    f4 Tn = {Bnv,Bnv,Bnv,Bnv};
    Tr=MF(hb00,wrf[0][0],Tr); Tr=MF(hb01,wrf[0][1],Tr);
    Tz=MF(hb00,wzf[0][0],Tz); Tz=MF(hb01,wzf[0][1],Tz);
    Tn=MF(hb00,wnf[0][0],Tn); Tn=MF(hb01,wnf[0][1],Tn);
    Tr=MF(ha0, wrf[1][0],Tr); Tr=MF(ha1, wrf[1][1],Tr);
    Tz=MF(ha0, wzf[1][0],Tz); Tz=MF(ha1, wzf[1][1],Tz);

    float zs[4], hs[4];
    if (q<2){
#pragma unroll
      for (int i=0;i<4;++i){
        int s4 = 4*q+i;
        float rg = sigm(Tr[i]);
        float ai = att_l[s4*SLEN + t];
        float zg = sigm(Tz[i]) * ai;
        float hold = hreg[i];
        zs[i]=zg; hs[i]=hold;
        rh_lds[s4][jc] = (unsigned short)fb1(rg*hold);
      }
    }
    sync_lds();                            // rh visible

    bf8s ra0 = *(const bf8s*)&rh_lds[l15][q*8];
    bf8s ra1 = *(const bf8s*)&rh_lds[l15][32+q*8];
    Tn=MF(ra0,wnf[1][0],Tn); Tn=MF(ra1,wnf[1][1],Tn);

    const int nb_=(t+1)&1;
    if (q<2){
#pragma unroll
      for (int i=0;i<4;++i){
        float ng = tanh_(Tn[i]);
        // zg==0 bypass: keeps NaN/garbage (t>=len) from touching h.
        float hnew = (zs[i]==0.f) ? hs[i] : (1.f-zs[i])*hs[i] + zs[i]*ng;
        hreg[i] = hnew;
        h_lds[nb_][4*q+i][jc] = (unsigned short)fb1(hnew);
      }
    }
    hb00=hb10; hb01=hb11; hb10=nb0; hb11=nb1;
    sync_lds();                            // h visible
  }
  if (q<2){
#pragma unroll
    for (int i=0;i<4;++i)
      out[(long)rows_s[4*q+i]*64 + jc] = hreg[i];
  }
}

extern "C" void kernel_launch(void* const* d_in, const int* in_sizes, int n_in,
                              void* d_out, int out_size, void* d_ws, size_t ws_size,
                              hipStream_t stream) {
  const void* behavior = d_in[0];
  const void* target   = d_in[1];
  const int*  lengths  = (const int*)d_in[2];
  const void* Wih = d_in[3];
  const void* Whh = d_in[4];
  const void* bih = d_in[5];
  const void* bhh = d_in[6];
  const void* A1  = d_in[7];
  const void* b1  = d_in[8];
  const void* A2  = d_in[9];
  const void* Wr  = d_in[10];
  const void* br  = d_in[11];
  const void* Wz  = d_in[12];
  const void* bz  = d_in[13];
  const void* Wn  = d_in[14];
  const void* bn  = d_in[15];

  int* flag = (int*)d_ws;
  unsigned short* hidden = (unsigned short*)((char*)d_ws + 256);
  float* attw = (float*)((char*)d_ws + 256 + (size_t)NB*SLEN*64*2);
  int* perm = (int*)((char*)d_ws + 256 + (size_t)NB*SLEN*64*2 + (size_t)NB*SLEN*4);
  size_t needed = 256 + (size_t)NB*SLEN*64*2 + (size_t)NB*SLEN*4 + (size_t)NB*4;
  if (ws_size < needed) return;

  k0_detect<<<1, 256, 0, stream>>>((const unsigned int*)behavior, 4096, flag);
  k0_sort  <<<1, 256, 0, stream>>>(lengths, perm);
  k1_gru  <<<NB/8, 256, 0, stream>>>(behavior, Wih, Whh, bih, bhh, lengths, perm, flag, hidden);
  k2_att  <<<NB,   256, 0, stream>>>(hidden, target, A1, b1, A2, lengths, flag, attw);
  k3_agru <<<NB/8, 256, 0, stream>>>(hidden, attw, Wr, br, Wz, bz, Wn, bn, lengths, perm, flag,
                                     (float*)d_out);
}